// Round 4
// baseline (339.873 us; speedup 1.0000x reference)
//
#include <hip/hip_runtime.h>

// GraphConv x3 on MI355X. R12: async gather via global_load_lds. R8/R10/R11
// all pinned at 56us: compiler never holds >2 register-landing gathers in
// flight (VGPR-pressure heuristic). Now gather loads are fire-and-forget
// global->LDS (zero VGPR landing), double-buffered 4KB chunks per wave
// (4 nodes x 4 edges), counted s_waitcnt vmcnt(4) mid-loop (never 0).
// Reduce reads chunks back via ds_read_b128. 5 dispatches.

#define C128 128
#define CAPN 64     // records per node; mean deg 16, Poisson tail ~1e-18

typedef short s16x8 __attribute__((ext_vector_type(8)));
typedef float f32x4 __attribute__((ext_vector_type(4)));

__device__ __forceinline__ ushort f2bf(float f) {        // RNE fp32->bf16
  unsigned u = __builtin_bit_cast(unsigned, f);
  u = (u + 0x7FFFu + ((u >> 16) & 1u)) >> 16;
  return (ushort)u;
}
__device__ __forceinline__ float bflo(unsigned v) {
  return __builtin_bit_cast(float, v << 16);
}
__device__ __forceinline__ float bfhi(unsigned v) {
  return __builtin_bit_cast(float, v & 0xFFFF0000u);
}
__device__ __forceinline__ unsigned pack2(float lo, float hi) {
  return (unsigned)f2bf(lo) | ((unsigned)f2bf(hi) << 16);
}
// async 16B global->LDS; lane i deposits at l + i*16; g is per-lane.
__device__ __forceinline__ void gload_lds16(const void* g, void* l) {
  __builtin_amdgcn_global_load_lds(
      (const __attribute__((address_space(1))) void*)g,
      (__attribute__((address_space(3))) void*)l, 16, 0, 0);
}

// ---------------------------------------------------------------------------
// prep: fused {input dropout fp32->bf16} + {weight pack} + {counter zero} +
// {nlist zero-fill}. Thread partition: [0,n4) dropout, [n4,+96K) pack,
// [+nCnt) zero ncnt, [+Npad*CAPN/8) zero nlist (uint4 strides).
// Wpack idx = (c*8+nt)*512 + lane*8 + j ->
//   W[o=nt*16+(lane&15)][k=(c&3)*32+(lane>>4)*8+j]; c<4 Wrel, c>=4 Wroot.
// ---------------------------------------------------------------------------
__global__ __launch_bounds__(256) void prep_kernel(const float* __restrict__ Wr0,
                                                   const float* __restrict__ Wt0,
                                                   const float* __restrict__ Wr1,
                                                   const float* __restrict__ Wt1,
                                                   const float* __restrict__ Wr2,
                                                   const float* __restrict__ Wt2,
                                                   ushort* __restrict__ Wpack,
                                                   const float* __restrict__ x,
                                                   const void* __restrict__ mask,
                                                   ushort* __restrict__ hdA,
                                                   int n4,
                                                   int* __restrict__ ncnt,
                                                   int nCnt,
                                                   uint4* __restrict__ nlist4,
                                                   int nL4) {
  int t = blockIdx.x * 256 + threadIdx.x;
  if (t < n4) {
    // per-wave mask dtype detect (wave fully inside this branch: n4 % 64 == 0)
    int lane = threadIdx.x & 63;
    unsigned mv = ((const unsigned*)mask)[lane];
    int m32 = (__ballot(mv > 1u) == 0ull);

    float4 v = ((const float4*)x)[t];
    int k0, k1, k2, k3;
    if (m32) {
      int4 m = ((const int4*)mask)[t];
      k0 = m.x; k1 = m.y; k2 = m.z; k3 = m.w;
    } else {
      uchar4 m = ((const uchar4*)mask)[t];
      k0 = m.x; k1 = m.y; k2 = m.z; k3 = m.w;
    }
    ushort4 r;
    r.x = k0 ? f2bf(v.x * 2.5f) : (ushort)0;
    r.y = k1 ? f2bf(v.y * 2.5f) : (ushort)0;
    r.z = k2 ? f2bf(v.z * 2.5f) : (ushort)0;
    r.w = k3 ? f2bf(v.w * 2.5f) : (ushort)0;
    ((ushort4*)hdA)[t] = r;
    return;
  }
  int u = t - n4;
  if (u < 3 * 32768) {
    int L = u >> 15;
    int r = u & 32767;
    int c = r >> 12;
    int nt = (r >> 9) & 7;
    int lane = (r >> 3) & 63;
    int j = r & 7;
    int o = nt * 16 + (lane & 15);
    int k = (c & 3) * 32 + (lane >> 4) * 8 + j;
    const float* src;
    if (L == 0)      src = (c < 4) ? Wr0 : Wt0;
    else if (L == 1) src = (c < 4) ? Wr1 : Wt1;
    else             src = (c < 4) ? Wr2 : Wt2;
    Wpack[u] = f2bf(src[o * C128 + k]);
    return;
  }
  int z = u - 3 * 32768;
  if (z < nCnt) { ncnt[z] = 0; return; }
  int z2 = z - nCnt;
  if (z2 < nL4) {
    uint4 zero; zero.x = 0; zero.y = 0; zero.z = 0; zero.w = 0;
    nlist4[z2] = zero;
  }
}

// ---------------------------------------------------------------------------
// fillb: edge -> per-node list, node-major (ushort src, N<65536).
// Counter line-padded (x16 ints). Edge dtype self-detected per wave.
// ---------------------------------------------------------------------------
__global__ __launch_bounds__(256) void fillb_kernel(const int* __restrict__ eidx,
                                                    int* __restrict__ ncnt,
                                                    ushort* __restrict__ nlist,
                                                    int E) {
  int lane = threadIdx.x & 63;
  unsigned long long be = __ballot(eidx[2 * lane + 1] != 0);
  int e64 = (be == 0ull);   // 1 = edges are int64
  int e = blockIdx.x * 256 + threadIdx.x;
  if (e >= E) return;
  int src, dst;
  if (e64) { src = eidx[2 * e]; dst = eidx[2 * E + 2 * e]; }
  else     { src = eidx[e];     dst = eidx[E + e]; }
  int pos = atomicAdd(&ncnt[dst * 16], 1);
  if (pos < CAPN) nlist[(size_t)dst * CAPN + pos] = (ushort)src;
}

// ---------------------------------------------------------------------------
// Fused layer: block = 16 nodes, 4 waves, wave w owns nodes 4w..4w+3.
//  0) stage: coalesced 512B list load per wave -> wl LDS (wave-private).
//  1) gather: async global_load_lds chunks (4 nodes x 4 edges = 4KB),
//     double-buffered; issue chunk c+2, s_waitcnt vmcnt(4), reduce chunk c
//     from LDS (ds_read_b128 + predicated fma, pad edges read row 0).
//     xor-shfl reduce over quads; quad-0 deposits bf16 rows into As. 1 barrier.
//  2) MFMA: wave w -> col tiles {2w,2w+1}; agg half from LDS, root half
//     loaded post-gather; B frags from Wpack (L2-hot).
//  3) epilogue: mode=1 ReLU + next dropout -> bf16; mode=0 +bias -> fp32.
// ---------------------------------------------------------------------------
__global__ __launch_bounds__(256, 4) void layer_kernel(const ushort* __restrict__ hd,
                                                       const int* __restrict__ ncnt,
                                                       const ushort* __restrict__ nlist,
                                                       const ushort* __restrict__ Wpack,
                                                       const float* __restrict__ bias,
                                                       const void* __restrict__ mask,
                                                       void* __restrict__ outp,
                                                       int mode, int N) {
  __shared__ ushort wl[16][CAPN];       // per-wave 4-row slices (512B/wave)
  __shared__ ushort As[16][136];        // 16 node rows, pad 8 (16B rows)
  __shared__ ushort gbuf[4][2][2048];   // per-wave dbuf: 2 x 4KB chunks

  const int tid = threadIdx.x;
  const int wave = tid >> 6, lane = tid & 63;
  const int quad = lane >> 4, l16 = lane & 15, co = l16 * 8;
  const int node0 = blockIdx.x * 16;
  const int nb0 = wave * 4;

  // mask dtype detect (wave-uniform ballot; cheap, L1/L2-hot broadcast)
  int m32 = 0;
  if (mode) {
    unsigned mv = ((const unsigned*)mask)[lane];
    m32 = (__ballot(mv > 1u) == 0ull);
  }

  // ---- 0) stage: degrees + this wave's 4 node lists ----
  int deg16 = ncnt[(node0 + l16) * 16];
  if (deg16 > CAPN) deg16 = CAPN;
  ((uint2*)&wl[nb0][0])[lane] =
      ((const uint2*)(nlist + (size_t)(node0 + nb0) * CAPN))[lane];

  int dc[4];
#pragma unroll
  for (int t = 0; t < 4; ++t) dc[t] = __shfl(deg16, nb0 + t, 64);
  int m = dc[0];
  if (dc[1] > m) m = dc[1];
  if (dc[2] > m) m = dc[2];
  if (dc[3] > m) m = dc[3];

  // ---- 1) gather: async LDS chunks, 4 edges/node/chunk ----
  const ushort* base = hd + co;
  float ag[4][8];
#pragma unroll
  for (int t = 0; t < 4; ++t)
#pragma unroll
    for (int i = 0; i < 8; ++i) ag[t][i] = 0.f;

  const int C = (m + 3) >> 2;          // wave-uniform chunk count (<=16)

  // issue chunk c into buffer b: inst t covers edges {4c+quad} of node t
#define ISSUE(c_, b_)                                                     \
  {                                                                       \
    const int e_ = ((c_) << 2) + quad;                                    \
    _Pragma("unroll")                                                     \
    for (int t_ = 0; t_ < 4; ++t_) {                                      \
      const ushort* g_ = base + (size_t)wl[nb0 + t_][e_] * C128;          \
      gload_lds16(g_, &gbuf[wave][b_][t_ * 512]);                         \
    }                                                                     \
  }

  if (C > 0) ISSUE(0, 0)
  if (C > 1) ISSUE(1, 1)

  for (int c = 0; c < C; ++c) {
    if (c + 1 < C) {
      asm volatile("s_waitcnt vmcnt(4)" ::: "memory");   // chunk c landed
    } else {
      asm volatile("s_waitcnt vmcnt(0)" ::: "memory");
    }
    __builtin_amdgcn_sched_barrier(0);
    const ushort* rb = &gbuf[wave][c & 1][lane * 8];
    const int e0 = (c << 2) + quad;
#pragma unroll
    for (int t = 0; t < 4; ++t) {
      uint4 v = *(const uint4*)(rb + t * 512);
      const float k = (e0 < dc[t]) ? 1.f : 0.f;
      ag[t][0] = fmaf(k, bflo(v.x), ag[t][0]);
      ag[t][1] = fmaf(k, bfhi(v.x), ag[t][1]);
      ag[t][2] = fmaf(k, bflo(v.y), ag[t][2]);
      ag[t][3] = fmaf(k, bfhi(v.y), ag[t][3]);
      ag[t][4] = fmaf(k, bflo(v.z), ag[t][4]);
      ag[t][5] = fmaf(k, bfhi(v.z), ag[t][5]);
      ag[t][6] = fmaf(k, bflo(v.w), ag[t][6]);
      ag[t][7] = fmaf(k, bfhi(v.w), ag[t][7]);
    }
    if (c + 2 < C) ISSUE(c + 2, c & 1)
  }
#undef ISSUE

#pragma unroll
  for (int t = 0; t < 4; ++t) {
#pragma unroll
    for (int i = 0; i < 8; ++i) {
      float v = ag[t][i];
      v += __shfl_xor(v, 16, 64);
      v += __shfl_xor(v, 32, 64);
      ag[t][i] = v;
    }
    if (quad == 0) {
      uint4 p;
      p.x = pack2(ag[t][0], ag[t][1]);
      p.y = pack2(ag[t][2], ag[t][3]);
      p.z = pack2(ag[t][4], ag[t][5]);
      p.w = pack2(ag[t][6], ag[t][7]);
      *(uint4*)&As[nb0 + t][co] = p;
    }
  }
  __syncthreads();

  // ---- 2) MFMA. Root frags loaded here (post-gather, TLP hides latency) ----
  int prow = node0 + l16;
  if (prow >= N) prow = N - 1;
  const ushort* hrow = hd + (size_t)prow * C128 + quad * 8;
  s16x8 aroot[4];
#pragma unroll
  for (int c = 0; c < 4; ++c) aroot[c] = *(const s16x8*)(hrow + c * 32);

  f32x4 acc[2];
  acc[0] = (f32x4)0.f;
  acc[1] = (f32x4)0.f;
  const ushort* wp = Wpack + lane * 8;
#pragma unroll
  for (int c = 0; c < 8; ++c) {
    s16x8 afr;
    if (c < 4) afr = *(const s16x8*)&As[l16][c * 32 + quad * 8];
    else       afr = aroot[c - 4];
#pragma unroll
    for (int j = 0; j < 2; ++j) {
      int nt = wave * 2 + j;
      s16x8 bfr = *(const s16x8*)(wp + (c * 8 + nt) * 512);
      acc[j] = __builtin_amdgcn_mfma_f32_16x16x32_bf16(afr, bfr, acc[j], 0, 0, 0);
    }
  }

  // ---- 3) epilogue. C/D layout: col = lane&15, row = quad*4 + reg ----
  if (mode) {
    ushort* ob = (ushort*)outp;
#pragma unroll
    for (int j = 0; j < 2; ++j) {
      int o = (wave * 2 + j) * 16 + l16;
      float bvv = bias[o];
#pragma unroll
      for (int r = 0; r < 4; ++r) {
        int node = node0 + quad * 4 + r;
        if (node >= N) continue;
        size_t idx = (size_t)node * C128 + o;
        int keep = m32 ? ((const int*)mask)[idx]
                       : (int)((const unsigned char*)mask)[idx];
        float v = fmaxf(acc[j][r] + bvv, 0.f);
        ob[idx] = keep ? f2bf(v * 2.5f) : (ushort)0;
      }
    }
  } else {
    float* of = (float*)outp;
#pragma unroll
    for (int j = 0; j < 2; ++j) {
      int o = (wave * 2 + j) * 16 + l16;
      float bvv = bias[o];
#pragma unroll
      for (int r = 0; r < 4; ++r) {
        int node = node0 + quad * 4 + r;
        if (node >= N) continue;
        of[(size_t)node * C128 + o] = acc[j][r] + bvv;
      }
    }
  }
}

// ---------------------------------------------------------------------------
extern "C" void kernel_launch(void* const* d_in, const int* in_sizes, int n_in,
                              void* d_out, int out_size, void* d_ws, size_t ws_size,
                              hipStream_t stream) {
  const float* x      = (const float*)d_in[0];
  const int*   eidx   = (const int*)d_in[1];
  const float* Wrel0  = (const float*)d_in[2];
  const float* Wroot0 = (const float*)d_in[3];
  const float* b0     = (const float*)d_in[4];
  const float* Wrel1  = (const float*)d_in[5];
  const float* Wroot1 = (const float*)d_in[6];
  const float* b1     = (const float*)d_in[7];
  const float* Wrel2  = (const float*)d_in[8];
  const float* Wroot2 = (const float*)d_in[9];
  const float* b2     = (const float*)d_in[10];
  const void*  drop0  = d_in[11];
  const void*  drop1  = d_in[12];
  const void*  drop2  = d_in[13];

  const int N       = in_sizes[0] / C128;
  const int E       = in_sizes[1] / 2;
  const int NC      = N * C128;
  const int nbuck16 = (N + 15) / 16;
  const int Npad    = nbuck16 * 16;
  const int nCnt    = Npad * 16;        // line-padded per-node counters
  const int nL4     = Npad * CAPN / 8;  // nlist size in uint4 units

  char*   ws    = (char*)d_ws;
  ushort* Wpack = (ushort*)ws;                           // 3*32768 bf16
  int*    ncnt  = (int*)(Wpack + 3 * 32768);             // nCnt ints
  ushort* nlist = (ushort*)(ncnt + nCnt);                // Npad*CAPN ushort
  ushort* hdA   = (ushort*)(nlist + (size_t)Npad * CAPN);
  ushort* hdB   = hdA + NC;

  const ushort* Wp0 = Wpack;
  const ushort* Wp1 = Wpack + 32768;
  const ushort* Wp2 = Wpack + 2 * 32768;

  const int n4    = NC / 4;
  const int prepT = n4 + 3 * 32768 + nCnt + nL4;
  prep_kernel<<<(prepT + 255) / 256, 256, 0, stream>>>(
      Wrel0, Wroot0, Wrel1, Wroot1, Wrel2, Wroot2, Wpack,
      x, drop0, hdA, n4, ncnt, nCnt, (uint4*)nlist, nL4);

  fillb_kernel<<<(E + 255) / 256, 256, 0, stream>>>(eidx, ncnt, nlist, E);

  // layer 0: hdA -> hdB (relu + drop1 fused)
  layer_kernel<<<nbuck16, 256, 0, stream>>>(hdA, ncnt, nlist, Wp0, b0, drop1,
                                            hdB, 1, N);
  // layer 1: hdB -> hdA (relu + drop2 fused)
  layer_kernel<<<nbuck16, 256, 0, stream>>>(hdB, ncnt, nlist, Wp1, b1, drop2,
                                            hdA, 1, N);
  // layer 2: hdA -> d_out (fp32)
  layer_kernel<<<nbuck16, 256, 0, stream>>>(hdA, ncnt, nlist, Wp2, b2, nullptr,
                                            d_out, 0, N);
}

// Round 5
// 332.823 us; speedup vs baseline: 1.0212x; 1.0212x over previous
//
#include <hip/hip_runtime.h>

// GraphConv x3 on MI355X. R13: shrink layer fetch. Layer FETCH_SIZE (98MB)
// decomposes as gather-miss ~50 + int32 dropout mask 25.6 + root hd 12.8 +
// nlist 6.4 + ncnt 3.2. Masks are now BIT-PACKED in prep (0.8MB per layer,
// epilogue reads one broadcast word per node: kb[node*4+wave], bit j*16+l16)
// and ncnt is un-padded (200KB). Gather machinery = R12 async global_load_lds
// double-buffered chunks, counted vmcnt (proven, kept). 5 dispatches.

#define C128 128
#define CAPN 64     // records per node; mean deg 16, Poisson tail ~1e-18

typedef short s16x8 __attribute__((ext_vector_type(8)));
typedef float f32x4 __attribute__((ext_vector_type(4)));

__device__ __forceinline__ ushort f2bf(float f) {        // RNE fp32->bf16
  unsigned u = __builtin_bit_cast(unsigned, f);
  u = (u + 0x7FFFu + ((u >> 16) & 1u)) >> 16;
  return (ushort)u;
}
__device__ __forceinline__ float bflo(unsigned v) {
  return __builtin_bit_cast(float, v << 16);
}
__device__ __forceinline__ float bfhi(unsigned v) {
  return __builtin_bit_cast(float, v & 0xFFFF0000u);
}
__device__ __forceinline__ unsigned pack2(float lo, float hi) {
  return (unsigned)f2bf(lo) | ((unsigned)f2bf(hi) << 16);
}
// async 16B global->LDS; lane i deposits at l + i*16; g is per-lane.
__device__ __forceinline__ void gload_lds16(const void* g, void* l) {
  __builtin_amdgcn_global_load_lds(
      (const __attribute__((address_space(1))) void*)g,
      (__attribute__((address_space(3))) void*)l, 16, 0, 0);
}
// mask dtype probe: 1 if mask is int32 (all of first 16 words are 0/1),
// 0 if uint8 (byte-packed 0/1 -> words like 0x00010001 > 1).
__device__ __forceinline__ int probe_m32(const void* msk) {
  const uint4* p = (const uint4*)msk;
  int m32 = 1;
#pragma unroll
  for (int i = 0; i < 4; ++i) {
    uint4 q = p[i];
    if (q.x > 1u || q.y > 1u || q.z > 1u || q.w > 1u) m32 = 0;
  }
  return m32;
}

// ---------------------------------------------------------------------------
// prep: fused {input dropout fp32->bf16} + {weight pack} + {ncnt zero} +
// {nlist zero} + {bit-pack drop1/drop2}. Thread partition (in order):
// [n4 dropout][98304 pack][Npad ncnt][nL4 nlist][2*NW mask-pack].
// Wpack idx = (c*8+nt)*512 + lane*8 + j ->
//   W[o=nt*16+(lane&15)][k=(c&3)*32+(lane>>4)*8+j]; c<4 Wrel, c>=4 Wroot.
// kb layout: kb[node*4 + w] bit b = keep(channel w*32+b).
// ---------------------------------------------------------------------------
__global__ __launch_bounds__(256) void prep_kernel(const float* __restrict__ Wr0,
                                                   const float* __restrict__ Wt0,
                                                   const float* __restrict__ Wr1,
                                                   const float* __restrict__ Wt1,
                                                   const float* __restrict__ Wr2,
                                                   const float* __restrict__ Wt2,
                                                   ushort* __restrict__ Wpack,
                                                   const float* __restrict__ x,
                                                   const void* __restrict__ mask0,
                                                   const void* __restrict__ mask1,
                                                   const void* __restrict__ mask2,
                                                   ushort* __restrict__ hdA,
                                                   unsigned* __restrict__ kb1,
                                                   unsigned* __restrict__ kb2,
                                                   int n4,
                                                   int* __restrict__ ncnt,
                                                   int Npad,
                                                   uint4* __restrict__ nlist4,
                                                   int nL4, int NW) {
  int t = blockIdx.x * 256 + threadIdx.x;
  if (t < n4) {
    int m32 = probe_m32(mask0);
    float4 v = ((const float4*)x)[t];
    int k0, k1, k2, k3;
    if (m32) {
      int4 m = ((const int4*)mask0)[t];
      k0 = m.x; k1 = m.y; k2 = m.z; k3 = m.w;
    } else {
      uchar4 m = ((const uchar4*)mask0)[t];
      k0 = m.x; k1 = m.y; k2 = m.z; k3 = m.w;
    }
    ushort4 r;
    r.x = k0 ? f2bf(v.x * 2.5f) : (ushort)0;
    r.y = k1 ? f2bf(v.y * 2.5f) : (ushort)0;
    r.z = k2 ? f2bf(v.z * 2.5f) : (ushort)0;
    r.w = k3 ? f2bf(v.w * 2.5f) : (ushort)0;
    ((ushort4*)hdA)[t] = r;
    return;
  }
  int u = t - n4;
  if (u < 3 * 32768) {
    int L = u >> 15;
    int r = u & 32767;
    int c = r >> 12;
    int nt = (r >> 9) & 7;
    int lane = (r >> 3) & 63;
    int j = r & 7;
    int o = nt * 16 + (lane & 15);
    int k = (c & 3) * 32 + (lane >> 4) * 8 + j;
    const float* src;
    if (L == 0)      src = (c < 4) ? Wr0 : Wt0;
    else if (L == 1) src = (c < 4) ? Wr1 : Wt1;
    else             src = (c < 4) ? Wr2 : Wt2;
    Wpack[u] = f2bf(src[o * C128 + k]);
    return;
  }
  u -= 3 * 32768;
  if (u < Npad) { ncnt[u] = 0; return; }
  u -= Npad;
  if (u < nL4) {
    uint4 zero; zero.x = 0; zero.y = 0; zero.z = 0; zero.w = 0;
    nlist4[u] = zero;
    return;
  }
  u -= nL4;
  if (u < 2 * NW) {
    const int L = (u >= NW);
    const int w = L ? u - NW : u;          // word id: node = w>>2, k = w&3
    const void* msk = L ? mask2 : mask1;
    const int n = w >> 2, k = w & 3;
    const int m32 = probe_m32(msk);
    unsigned wb = 0;
    if (m32) {
      const int4* b = (const int4*)msk + n * 32 + k * 8;
#pragma unroll
      for (int i = 0; i < 8; ++i) {
        int4 mm = b[i];
        wb |= (mm.x ? 1u : 0u) << (4 * i);
        wb |= (mm.y ? 1u : 0u) << (4 * i + 1);
        wb |= (mm.z ? 1u : 0u) << (4 * i + 2);
        wb |= (mm.w ? 1u : 0u) << (4 * i + 3);
      }
    } else {
      const uchar4* b = (const uchar4*)msk + n * 32 + k * 8;
#pragma unroll
      for (int i = 0; i < 8; ++i) {
        uchar4 mm = b[i];
        wb |= (mm.x ? 1u : 0u) << (4 * i);
        wb |= (mm.y ? 1u : 0u) << (4 * i + 1);
        wb |= (mm.z ? 1u : 0u) << (4 * i + 2);
        wb |= (mm.w ? 1u : 0u) << (4 * i + 3);
      }
    }
    (L ? kb2 : kb1)[n * 4 + k] = wb;
  }
}

// ---------------------------------------------------------------------------
// fillb: edge -> per-node list, node-major (ushort src, N<65536).
// ncnt un-padded (200KB, L2-hot; ~16 edges/counter contention is cheap).
// Edge dtype self-detected per wave (all 64 lanes active pre-guard).
// ---------------------------------------------------------------------------
__global__ __launch_bounds__(256) void fillb_kernel(const int* __restrict__ eidx,
                                                    int* __restrict__ ncnt,
                                                    ushort* __restrict__ nlist,
                                                    int E) {
  int lane = threadIdx.x & 63;
  unsigned long long be = __ballot(eidx[2 * lane + 1] != 0);
  int e64 = (be == 0ull);   // 1 = edges are int64
  int e = blockIdx.x * 256 + threadIdx.x;
  if (e >= E) return;
  int src, dst;
  if (e64) { src = eidx[2 * e]; dst = eidx[2 * E + 2 * e]; }
  else     { src = eidx[e];     dst = eidx[E + e]; }
  int pos = atomicAdd(&ncnt[dst], 1);
  if (pos < CAPN) nlist[(size_t)dst * CAPN + pos] = (ushort)src;
}

// ---------------------------------------------------------------------------
// Fused layer: block = 16 nodes, 4 waves, wave w owns nodes 4w..4w+3.
//  0) stage: coalesced 512B list load per wave -> wl LDS + 16 coalesced
//     degree loads (ncnt un-padded).
//  1) gather: async global_load_lds chunks (4 nodes x 4 edges = 4KB),
//     double-buffered; counted s_waitcnt vmcnt(4) mid-loop; predicated fma;
//     pad edges read row 0 (nlist zero-filled). xor-shfl reduce over quads;
//     quad-0 deposits bf16 rows into As. 1 barrier.
//  2) MFMA: wave w -> col tiles {2w,2w+1}; agg half from LDS, root half
//     loaded post-gather; B frags from Wpack (L2-hot).
//  3) epilogue: mode=1 ReLU + bit-packed next-dropout -> bf16 (mask word =
//     kb[node*4+wave], bit j*16+l16); mode=0 +bias -> fp32.
// ---------------------------------------------------------------------------
__global__ __launch_bounds__(256, 4) void layer_kernel(const ushort* __restrict__ hd,
                                                       const int* __restrict__ ncnt,
                                                       const ushort* __restrict__ nlist,
                                                       const ushort* __restrict__ Wpack,
                                                       const float* __restrict__ bias,
                                                       const unsigned* __restrict__ kb,
                                                       void* __restrict__ outp,
                                                       int mode, int N) {
  __shared__ ushort wl[16][CAPN];       // per-wave 4-row slices (512B/wave)
  __shared__ ushort As[16][136];        // 16 node rows, pad 8 (16B rows)
  __shared__ ushort gbuf[4][2][2048];   // per-wave dbuf: 2 x 4KB chunks

  const int tid = threadIdx.x;
  const int wave = tid >> 6, lane = tid & 63;
  const int quad = lane >> 4, l16 = lane & 15, co = l16 * 8;
  const int node0 = blockIdx.x * 16;
  const int nb0 = wave * 4;

  // ---- 0) stage: degrees + this wave's 4 node lists ----
  int deg16 = ncnt[node0 + l16];
  if (deg16 > CAPN) deg16 = CAPN;
  ((uint2*)&wl[nb0][0])[lane] =
      ((const uint2*)(nlist + (size_t)(node0 + nb0) * CAPN))[lane];

  int dc[4];
#pragma unroll
  for (int t = 0; t < 4; ++t) dc[t] = __shfl(deg16, nb0 + t, 64);
  int m = dc[0];
  if (dc[1] > m) m = dc[1];
  if (dc[2] > m) m = dc[2];
  if (dc[3] > m) m = dc[3];

  // ---- 1) gather: async LDS chunks, 4 edges/node/chunk ----
  const ushort* base = hd + co;
  float ag[4][8];
#pragma unroll
  for (int t = 0; t < 4; ++t)
#pragma unroll
    for (int i = 0; i < 8; ++i) ag[t][i] = 0.f;

  const int C = (m + 3) >> 2;          // wave-uniform chunk count (<=16)

#define ISSUE(c_, b_)                                                     \
  {                                                                       \
    const int e_ = ((c_) << 2) + quad;                                    \
    _Pragma("unroll")                                                     \
    for (int t_ = 0; t_ < 4; ++t_) {                                      \
      const ushort* g_ = base + (size_t)wl[nb0 + t_][e_] * C128;          \
      gload_lds16(g_, &gbuf[wave][b_][t_ * 512]);                         \
    }                                                                     \
  }

  if (C > 0) ISSUE(0, 0)
  if (C > 1) ISSUE(1, 1)

  for (int c = 0; c < C; ++c) {
    if (c + 1 < C) {
      asm volatile("s_waitcnt vmcnt(4)" ::: "memory");   // chunk c landed
    } else {
      asm volatile("s_waitcnt vmcnt(0)" ::: "memory");
    }
    __builtin_amdgcn_sched_barrier(0);
    const ushort* rb = &gbuf[wave][c & 1][lane * 8];
    const int e0 = (c << 2) + quad;
#pragma unroll
    for (int t = 0; t < 4; ++t) {
      uint4 v = *(const uint4*)(rb + t * 512);
      const float k = (e0 < dc[t]) ? 1.f : 0.f;
      ag[t][0] = fmaf(k, bflo(v.x), ag[t][0]);
      ag[t][1] = fmaf(k, bfhi(v.x), ag[t][1]);
      ag[t][2] = fmaf(k, bflo(v.y), ag[t][2]);
      ag[t][3] = fmaf(k, bfhi(v.y), ag[t][3]);
      ag[t][4] = fmaf(k, bflo(v.z), ag[t][4]);
      ag[t][5] = fmaf(k, bfhi(v.z), ag[t][5]);
      ag[t][6] = fmaf(k, bflo(v.w), ag[t][6]);
      ag[t][7] = fmaf(k, bfhi(v.w), ag[t][7]);
    }
    if (c + 2 < C) ISSUE(c + 2, c & 1)
  }
#undef ISSUE

#pragma unroll
  for (int t = 0; t < 4; ++t) {
#pragma unroll
    for (int i = 0; i < 8; ++i) {
      float v = ag[t][i];
      v += __shfl_xor(v, 16, 64);
      v += __shfl_xor(v, 32, 64);
      ag[t][i] = v;
    }
    if (quad == 0) {
      uint4 p;
      p.x = pack2(ag[t][0], ag[t][1]);
      p.y = pack2(ag[t][2], ag[t][3]);
      p.z = pack2(ag[t][4], ag[t][5]);
      p.w = pack2(ag[t][6], ag[t][7]);
      *(uint4*)&As[nb0 + t][co] = p;
    }
  }
  __syncthreads();

  // ---- 2) MFMA. Root frags loaded here (post-gather, TLP hides latency) ----
  int prow = node0 + l16;
  if (prow >= N) prow = N - 1;
  const ushort* hrow = hd + (size_t)prow * C128 + quad * 8;
  s16x8 aroot[4];
#pragma unroll
  for (int c = 0; c < 4; ++c) aroot[c] = *(const s16x8*)(hrow + c * 32);

  f32x4 acc[2];
  acc[0] = (f32x4)0.f;
  acc[1] = (f32x4)0.f;
  const ushort* wp = Wpack + lane * 8;
#pragma unroll
  for (int c = 0; c < 8; ++c) {
    s16x8 afr;
    if (c < 4) afr = *(const s16x8*)&As[l16][c * 32 + quad * 8];
    else       afr = aroot[c - 4];
#pragma unroll
    for (int j = 0; j < 2; ++j) {
      int nt = wave * 2 + j;
      s16x8 bfr = *(const s16x8*)(wp + (c * 8 + nt) * 512);
      acc[j] = __builtin_amdgcn_mfma_f32_16x16x32_bf16(afr, bfr, acc[j], 0, 0, 0);
    }
  }

  // ---- 3) epilogue. C/D layout: col = lane&15, row = quad*4 + reg ----
  float bv[2];
#pragma unroll
  for (int j = 0; j < 2; ++j) bv[j] = bias[(wave * 2 + j) * 16 + l16];

  if (mode) {
    ushort* ob = (ushort*)outp;
#pragma unroll
    for (int r = 0; r < 4; ++r) {
      int node = node0 + quad * 4 + r;
      if (node >= N) continue;
      unsigned kw = kb[node * 4 + wave];   // broadcast within 16-lane group
#pragma unroll
      for (int j = 0; j < 2; ++j) {
        int o = (wave * 2 + j) * 16 + l16;
        float v = fmaxf(acc[j][r] + bv[j], 0.f);
        ob[(size_t)node * C128 + o] =
            ((kw >> (j * 16 + l16)) & 1u) ? f2bf(v * 2.5f) : (ushort)0;
      }
    }
  } else {
    float* of = (float*)outp;
#pragma unroll
    for (int r = 0; r < 4; ++r) {
      int node = node0 + quad * 4 + r;
      if (node >= N) continue;
#pragma unroll
      for (int j = 0; j < 2; ++j) {
        int o = (wave * 2 + j) * 16 + l16;
        of[(size_t)node * C128 + o] = acc[j][r] + bv[j];
      }
    }
  }
}

// ---------------------------------------------------------------------------
extern "C" void kernel_launch(void* const* d_in, const int* in_sizes, int n_in,
                              void* d_out, int out_size, void* d_ws, size_t ws_size,
                              hipStream_t stream) {
  const float* x      = (const float*)d_in[0];
  const int*   eidx   = (const int*)d_in[1];
  const float* Wrel0  = (const float*)d_in[2];
  const float* Wroot0 = (const float*)d_in[3];
  const float* b0     = (const float*)d_in[4];
  const float* Wrel1  = (const float*)d_in[5];
  const float* Wroot1 = (const float*)d_in[6];
  const float* b1     = (const float*)d_in[7];
  const float* Wrel2  = (const float*)d_in[8];
  const float* Wroot2 = (const float*)d_in[9];
  const float* b2     = (const float*)d_in[10];
  const void*  drop0  = d_in[11];
  const void*  drop1  = d_in[12];
  const void*  drop2  = d_in[13];

  const int N       = in_sizes[0] / C128;
  const int E       = in_sizes[1] / 2;
  const int NC      = N * C128;
  const int nbuck16 = (N + 15) / 16;
  const int Npad    = nbuck16 * 16;
  const int nL4     = Npad * CAPN / 8;  // nlist size in uint4 units
  const int NW      = N * 4;            // mask words per layer

  char*     ws    = (char*)d_ws;
  ushort*   Wpack = (ushort*)ws;                          // 196608 B
  int*      ncnt  = (int*)(Wpack + 3 * 32768);            // Npad ints
  unsigned* kb1   = (unsigned*)(ncnt + Npad);             // Npad*4 uints
  unsigned* kb2   = kb1 + (size_t)Npad * 4;               // Npad*4 uints
  ushort*   nlist = (ushort*)(kb2 + (size_t)Npad * 4);    // Npad*CAPN ushort
  ushort*   hdA   = (ushort*)(nlist + (size_t)Npad * CAPN);
  ushort*   hdB   = hdA + NC;

  const ushort* Wp0 = Wpack;
  const ushort* Wp1 = Wpack + 32768;
  const ushort* Wp2 = Wpack + 2 * 32768;

  const int n4    = NC / 4;
  const int prepT = n4 + 3 * 32768 + Npad + nL4 + 2 * NW;
  prep_kernel<<<(prepT + 255) / 256, 256, 0, stream>>>(
      Wrel0, Wroot0, Wrel1, Wroot1, Wrel2, Wroot2, Wpack,
      x, drop0, drop1, drop2, hdA, kb1, kb2, n4, ncnt, Npad,
      (uint4*)nlist, nL4, NW);

  fillb_kernel<<<(E + 255) / 256, 256, 0, stream>>>(eidx, ncnt, nlist, E);

  // layer 0: hdA -> hdB (relu + drop1 fused)
  layer_kernel<<<nbuck16, 256, 0, stream>>>(hdA, ncnt, nlist, Wp0, b0, kb1,
                                            hdB, 1, N);
  // layer 1: hdB -> hdA (relu + drop2 fused)
  layer_kernel<<<nbuck16, 256, 0, stream>>>(hdB, ncnt, nlist, Wp1, b1, kb2,
                                            hdA, 1, N);
  // layer 2: hdA -> d_out (fp32)
  layer_kernel<<<nbuck16, 256, 0, stream>>>(hdA, ncnt, nlist, Wp2, b2, nullptr,
                                            d_out, 0, N);
}

// Round 6
// 324.696 us; speedup vs baseline: 1.0467x; 1.0250x over previous
//
#include <hip/hip_runtime.h>

// GraphConv x3 on MI355X. R14: XCD-local fillb. R13's fillb wrote 44MB HBM
// for a 6.4MB nlist (random 2B scatter from all 8 XCDs -> non-coherent L2s
// flush partial lines individually). Now dst-space is split into 8 segments;
// seg = blockIdx&7 (XCD round-robin proxy); each (seg,chunk) block scans a
// 256-edge chunk and keeps only its segment's edges -> all writes to a line
// come from ONE XCD -> L2-resident, written back once. Edge list re-reads
// (8x) ride the 256MB L3. Layers = R13 (async global_load_lds gather,
// bit-packed dropout, proven). 5 dispatches.

#define C128 128
#define CAPN 64     // records per node; mean deg 16, Poisson tail ~1e-18
#define NSEG 8

typedef short s16x8 __attribute__((ext_vector_type(8)));
typedef float f32x4 __attribute__((ext_vector_type(4)));

__device__ __forceinline__ ushort f2bf(float f) {        // RNE fp32->bf16
  unsigned u = __builtin_bit_cast(unsigned, f);
  u = (u + 0x7FFFu + ((u >> 16) & 1u)) >> 16;
  return (ushort)u;
}
__device__ __forceinline__ float bflo(unsigned v) {
  return __builtin_bit_cast(float, v << 16);
}
__device__ __forceinline__ float bfhi(unsigned v) {
  return __builtin_bit_cast(float, v & 0xFFFF0000u);
}
__device__ __forceinline__ unsigned pack2(float lo, float hi) {
  return (unsigned)f2bf(lo) | ((unsigned)f2bf(hi) << 16);
}
// async 16B global->LDS; lane i deposits at l + i*16; g is per-lane.
__device__ __forceinline__ void gload_lds16(const void* g, void* l) {
  __builtin_amdgcn_global_load_lds(
      (const __attribute__((address_space(1))) void*)g,
      (__attribute__((address_space(3))) void*)l, 16, 0, 0);
}
// mask dtype probe: 1 if mask is int32 (all of first 16 words are 0/1),
// 0 if uint8 (byte-packed 0/1 -> words like 0x00010001 > 1).
__device__ __forceinline__ int probe_m32(const void* msk) {
  const uint4* p = (const uint4*)msk;
  int m32 = 1;
#pragma unroll
  for (int i = 0; i < 4; ++i) {
    uint4 q = p[i];
    if (q.x > 1u || q.y > 1u || q.z > 1u || q.w > 1u) m32 = 0;
  }
  return m32;
}

// ---------------------------------------------------------------------------
// prep: fused {input dropout fp32->bf16} + {weight pack} + {ncnt zero} +
// {nlist zero} + {bit-pack drop1/drop2}. Thread partition (in order):
// [n4 dropout][98304 pack][Npad ncnt][nL4 nlist][2*NW mask-pack].
// Wpack idx = (c*8+nt)*512 + lane*8 + j ->
//   W[o=nt*16+(lane&15)][k=(c&3)*32+(lane>>4)*8+j]; c<4 Wrel, c>=4 Wroot.
// kb layout: kb[node*4 + w] bit b = keep(channel w*32+b).
// ---------------------------------------------------------------------------
__global__ __launch_bounds__(256) void prep_kernel(const float* __restrict__ Wr0,
                                                   const float* __restrict__ Wt0,
                                                   const float* __restrict__ Wr1,
                                                   const float* __restrict__ Wt1,
                                                   const float* __restrict__ Wr2,
                                                   const float* __restrict__ Wt2,
                                                   ushort* __restrict__ Wpack,
                                                   const float* __restrict__ x,
                                                   const void* __restrict__ mask0,
                                                   const void* __restrict__ mask1,
                                                   const void* __restrict__ mask2,
                                                   ushort* __restrict__ hdA,
                                                   unsigned* __restrict__ kb1,
                                                   unsigned* __restrict__ kb2,
                                                   int n4,
                                                   int* __restrict__ ncnt,
                                                   int Npad,
                                                   uint4* __restrict__ nlist4,
                                                   int nL4, int NW) {
  int t = blockIdx.x * 256 + threadIdx.x;
  if (t < n4) {
    int m32 = probe_m32(mask0);
    float4 v = ((const float4*)x)[t];
    int k0, k1, k2, k3;
    if (m32) {
      int4 m = ((const int4*)mask0)[t];
      k0 = m.x; k1 = m.y; k2 = m.z; k3 = m.w;
    } else {
      uchar4 m = ((const uchar4*)mask0)[t];
      k0 = m.x; k1 = m.y; k2 = m.z; k3 = m.w;
    }
    ushort4 r;
    r.x = k0 ? f2bf(v.x * 2.5f) : (ushort)0;
    r.y = k1 ? f2bf(v.y * 2.5f) : (ushort)0;
    r.z = k2 ? f2bf(v.z * 2.5f) : (ushort)0;
    r.w = k3 ? f2bf(v.w * 2.5f) : (ushort)0;
    ((ushort4*)hdA)[t] = r;
    return;
  }
  int u = t - n4;
  if (u < 3 * 32768) {
    int L = u >> 15;
    int r = u & 32767;
    int c = r >> 12;
    int nt = (r >> 9) & 7;
    int lane = (r >> 3) & 63;
    int j = r & 7;
    int o = nt * 16 + (lane & 15);
    int k = (c & 3) * 32 + (lane >> 4) * 8 + j;
    const float* src;
    if (L == 0)      src = (c < 4) ? Wr0 : Wt0;
    else if (L == 1) src = (c < 4) ? Wr1 : Wt1;
    else             src = (c < 4) ? Wr2 : Wt2;
    Wpack[u] = f2bf(src[o * C128 + k]);
    return;
  }
  u -= 3 * 32768;
  if (u < Npad) { ncnt[u] = 0; return; }
  u -= Npad;
  if (u < nL4) {
    uint4 zero; zero.x = 0; zero.y = 0; zero.z = 0; zero.w = 0;
    nlist4[u] = zero;
    return;
  }
  u -= nL4;
  if (u < 2 * NW) {
    const int L = (u >= NW);
    const int w = L ? u - NW : u;          // word id: node = w>>2, k = w&3
    const void* msk = L ? mask2 : mask1;
    const int n = w >> 2, k = w & 3;
    const int m32 = probe_m32(msk);
    unsigned wb = 0;
    if (m32) {
      const int4* b = (const int4*)msk + n * 32 + k * 8;
#pragma unroll
      for (int i = 0; i < 8; ++i) {
        int4 mm = b[i];
        wb |= (mm.x ? 1u : 0u) << (4 * i);
        wb |= (mm.y ? 1u : 0u) << (4 * i + 1);
        wb |= (mm.z ? 1u : 0u) << (4 * i + 2);
        wb |= (mm.w ? 1u : 0u) << (4 * i + 3);
      }
    } else {
      const uchar4* b = (const uchar4*)msk + n * 32 + k * 8;
#pragma unroll
      for (int i = 0; i < 8; ++i) {
        uchar4 mm = b[i];
        wb |= (mm.x ? 1u : 0u) << (4 * i);
        wb |= (mm.y ? 1u : 0u) << (4 * i + 1);
        wb |= (mm.z ? 1u : 0u) << (4 * i + 2);
        wb |= (mm.w ? 1u : 0u) << (4 * i + 3);
      }
    }
    (L ? kb2 : kb1)[n * 4 + k] = wb;
  }
}

// ---------------------------------------------------------------------------
// fillb: XCD-local segment scan. seg = blockIdx&7 (XCD round-robin proxy)
// owns dst in [seg*segsz, (seg+1)*segsz). Block (seg,chunk) scans edges
// [chunk*256, +256) and scatters only its segment's -> every nlist/ncnt line
// written by ONE XCD -> stays in that L2, one write-back. Edge list re-reads
// ride L3. Edge dtype self-detected per wave.
// ---------------------------------------------------------------------------
__global__ __launch_bounds__(256) void fillb_kernel(const int* __restrict__ eidx,
                                                    int* __restrict__ ncnt,
                                                    ushort* __restrict__ nlist,
                                                    int E, int segsz) {
  int lane = threadIdx.x & 63;
  unsigned long long be = __ballot(eidx[2 * lane + 1] != 0);
  int e64 = (be == 0ull);   // 1 = edges are int64
  const int seg = blockIdx.x & (NSEG - 1);
  const int chunk = blockIdx.x >> 3;
  const int lo = seg * segsz, hi = lo + segsz;
  int e = chunk * 256 + threadIdx.x;
  if (e >= E) return;
  int dst;
  if (e64) dst = eidx[2 * E + 2 * e];
  else     dst = eidx[E + e];
  if (dst < lo || dst >= hi) return;
  int src = e64 ? eidx[2 * e] : eidx[e];
  int pos = atomicAdd(&ncnt[dst], 1);
  if (pos < CAPN) nlist[(size_t)dst * CAPN + pos] = (ushort)src;
}

// ---------------------------------------------------------------------------
// Fused layer: block = 16 nodes, 4 waves, wave w owns nodes 4w..4w+3.
//  0) stage: coalesced 512B list load per wave -> wl LDS + 16 coalesced
//     degree loads.
//  1) gather: async global_load_lds chunks (4 nodes x 4 edges = 4KB),
//     double-buffered; counted s_waitcnt vmcnt(4) mid-loop; predicated fma;
//     pad edges read row 0 (nlist zero-filled). xor-shfl reduce over quads;
//     quad-0 deposits bf16 rows into As. 1 barrier.
//  2) MFMA: wave w -> col tiles {2w,2w+1}; agg half from LDS, root half
//     loaded post-gather; B frags from Wpack (L2-hot).
//  3) epilogue: mode=1 ReLU + bit-packed next-dropout -> bf16 (mask word =
//     kb[node*4+wave], bit j*16+l16); mode=0 +bias -> fp32.
// ---------------------------------------------------------------------------
__global__ __launch_bounds__(256, 4) void layer_kernel(const ushort* __restrict__ hd,
                                                       const int* __restrict__ ncnt,
                                                       const ushort* __restrict__ nlist,
                                                       const ushort* __restrict__ Wpack,
                                                       const float* __restrict__ bias,
                                                       const unsigned* __restrict__ kb,
                                                       void* __restrict__ outp,
                                                       int mode, int N) {
  __shared__ ushort wl[16][CAPN];       // per-wave 4-row slices (512B/wave)
  __shared__ ushort As[16][136];        // 16 node rows, pad 8 (16B rows)
  __shared__ ushort gbuf[4][2][2048];   // per-wave dbuf: 2 x 4KB chunks

  const int tid = threadIdx.x;
  const int wave = tid >> 6, lane = tid & 63;
  const int quad = lane >> 4, l16 = lane & 15, co = l16 * 8;
  const int node0 = blockIdx.x * 16;
  const int nb0 = wave * 4;

  // ---- 0) stage: degrees + this wave's 4 node lists ----
  int deg16 = ncnt[node0 + l16];
  if (deg16 > CAPN) deg16 = CAPN;
  ((uint2*)&wl[nb0][0])[lane] =
      ((const uint2*)(nlist + (size_t)(node0 + nb0) * CAPN))[lane];

  int dc[4];
#pragma unroll
  for (int t = 0; t < 4; ++t) dc[t] = __shfl(deg16, nb0 + t, 64);
  int m = dc[0];
  if (dc[1] > m) m = dc[1];
  if (dc[2] > m) m = dc[2];
  if (dc[3] > m) m = dc[3];

  // ---- 1) gather: async LDS chunks, 4 edges/node/chunk ----
  const ushort* base = hd + co;
  float ag[4][8];
#pragma unroll
  for (int t = 0; t < 4; ++t)
#pragma unroll
    for (int i = 0; i < 8; ++i) ag[t][i] = 0.f;

  const int C = (m + 3) >> 2;          // wave-uniform chunk count (<=16)

#define ISSUE(c_, b_)                                                     \
  {                                                                       \
    const int e_ = ((c_) << 2) + quad;                                    \
    _Pragma("unroll")                                                     \
    for (int t_ = 0; t_ < 4; ++t_) {                                      \
      const ushort* g_ = base + (size_t)wl[nb0 + t_][e_] * C128;          \
      gload_lds16(g_, &gbuf[wave][b_][t_ * 512]);                         \
    }                                                                     \
  }

  if (C > 0) ISSUE(0, 0)
  if (C > 1) ISSUE(1, 1)

  for (int c = 0; c < C; ++c) {
    if (c + 1 < C) {
      asm volatile("s_waitcnt vmcnt(4)" ::: "memory");   // chunk c landed
    } else {
      asm volatile("s_waitcnt vmcnt(0)" ::: "memory");
    }
    __builtin_amdgcn_sched_barrier(0);
    const ushort* rb = &gbuf[wave][c & 1][lane * 8];
    const int e0 = (c << 2) + quad;
#pragma unroll
    for (int t = 0; t < 4; ++t) {
      uint4 v = *(const uint4*)(rb + t * 512);
      const float k = (e0 < dc[t]) ? 1.f : 0.f;
      ag[t][0] = fmaf(k, bflo(v.x), ag[t][0]);
      ag[t][1] = fmaf(k, bfhi(v.x), ag[t][1]);
      ag[t][2] = fmaf(k, bflo(v.y), ag[t][2]);
      ag[t][3] = fmaf(k, bfhi(v.y), ag[t][3]);
      ag[t][4] = fmaf(k, bflo(v.z), ag[t][4]);
      ag[t][5] = fmaf(k, bfhi(v.z), ag[t][5]);
      ag[t][6] = fmaf(k, bflo(v.w), ag[t][6]);
      ag[t][7] = fmaf(k, bfhi(v.w), ag[t][7]);
    }
    if (c + 2 < C) ISSUE(c + 2, c & 1)
  }
#undef ISSUE

#pragma unroll
  for (int t = 0; t < 4; ++t) {
#pragma unroll
    for (int i = 0; i < 8; ++i) {
      float v = ag[t][i];
      v += __shfl_xor(v, 16, 64);
      v += __shfl_xor(v, 32, 64);
      ag[t][i] = v;
    }
    if (quad == 0) {
      uint4 p;
      p.x = pack2(ag[t][0], ag[t][1]);
      p.y = pack2(ag[t][2], ag[t][3]);
      p.z = pack2(ag[t][4], ag[t][5]);
      p.w = pack2(ag[t][6], ag[t][7]);
      *(uint4*)&As[nb0 + t][co] = p;
    }
  }
  __syncthreads();

  // ---- 2) MFMA. Root frags loaded here (post-gather, TLP hides latency) ----
  int prow = node0 + l16;
  if (prow >= N) prow = N - 1;
  const ushort* hrow = hd + (size_t)prow * C128 + quad * 8;
  s16x8 aroot[4];
#pragma unroll
  for (int c = 0; c < 4; ++c) aroot[c] = *(const s16x8*)(hrow + c * 32);

  f32x4 acc[2];
  acc[0] = (f32x4)0.f;
  acc[1] = (f32x4)0.f;
  const ushort* wp = Wpack + lane * 8;
#pragma unroll
  for (int c = 0; c < 8; ++c) {
    s16x8 afr;
    if (c < 4) afr = *(const s16x8*)&As[l16][c * 32 + quad * 8];
    else       afr = aroot[c - 4];
#pragma unroll
    for (int j = 0; j < 2; ++j) {
      int nt = wave * 2 + j;
      s16x8 bfr = *(const s16x8*)(wp + (c * 8 + nt) * 512);
      acc[j] = __builtin_amdgcn_mfma_f32_16x16x32_bf16(afr, bfr, acc[j], 0, 0, 0);
    }
  }

  // ---- 3) epilogue. C/D layout: col = lane&15, row = quad*4 + reg ----
  float bv[2];
#pragma unroll
  for (int j = 0; j < 2; ++j) bv[j] = bias[(wave * 2 + j) * 16 + l16];

  if (mode) {
    ushort* ob = (ushort*)outp;
#pragma unroll
    for (int r = 0; r < 4; ++r) {
      int node = node0 + quad * 4 + r;
      if (node >= N) continue;
      unsigned kw = kb[node * 4 + wave];   // broadcast within 16-lane group
#pragma unroll
      for (int j = 0; j < 2; ++j) {
        int o = (wave * 2 + j) * 16 + l16;
        float v = fmaxf(acc[j][r] + bv[j], 0.f);
        ob[(size_t)node * C128 + o] =
            ((kw >> (j * 16 + l16)) & 1u) ? f2bf(v * 2.5f) : (ushort)0;
      }
    }
  } else {
    float* of = (float*)outp;
#pragma unroll
    for (int r = 0; r < 4; ++r) {
      int node = node0 + quad * 4 + r;
      if (node >= N) continue;
#pragma unroll
      for (int j = 0; j < 2; ++j) {
        int o = (wave * 2 + j) * 16 + l16;
        of[(size_t)node * C128 + o] = acc[j][r] + bv[j];
      }
    }
  }
}

// ---------------------------------------------------------------------------
extern "C" void kernel_launch(void* const* d_in, const int* in_sizes, int n_in,
                              void* d_out, int out_size, void* d_ws, size_t ws_size,
                              hipStream_t stream) {
  const float* x      = (const float*)d_in[0];
  const int*   eidx   = (const int*)d_in[1];
  const float* Wrel0  = (const float*)d_in[2];
  const float* Wroot0 = (const float*)d_in[3];
  const float* b0     = (const float*)d_in[4];
  const float* Wrel1  = (const float*)d_in[5];
  const float* Wroot1 = (const float*)d_in[6];
  const float* b1     = (const float*)d_in[7];
  const float* Wrel2  = (const float*)d_in[8];
  const float* Wroot2 = (const float*)d_in[9];
  const float* b2     = (const float*)d_in[10];
  const void*  drop0  = d_in[11];
  const void*  drop1  = d_in[12];
  const void*  drop2  = d_in[13];

  const int N       = in_sizes[0] / C128;
  const int E       = in_sizes[1] / 2;
  const int NC      = N * C128;
  const int nbuck16 = (N + 15) / 16;
  const int Npad    = nbuck16 * 16;
  const int nL4     = Npad * CAPN / 8;  // nlist size in uint4 units
  const int NW      = N * 4;            // mask words per layer
  const int segsz   = (Npad + NSEG - 1) / NSEG;

  char*     ws    = (char*)d_ws;
  ushort*   Wpack = (ushort*)ws;                          // 196608 B
  int*      ncnt  = (int*)(Wpack + 3 * 32768);            // Npad ints
  unsigned* kb1   = (unsigned*)(ncnt + Npad);             // Npad*4 uints
  unsigned* kb2   = kb1 + (size_t)Npad * 4;               // Npad*4 uints
  ushort*   nlist = (ushort*)(kb2 + (size_t)Npad * 4);    // Npad*CAPN ushort
  ushort*   hdA   = (ushort*)(nlist + (size_t)Npad * CAPN);
  ushort*   hdB   = hdA + NC;

  const ushort* Wp0 = Wpack;
  const ushort* Wp1 = Wpack + 32768;
  const ushort* Wp2 = Wpack + 2 * 32768;

  const int n4    = NC / 4;
  const int prepT = n4 + 3 * 32768 + Npad + nL4 + 2 * NW;
  prep_kernel<<<(prepT + 255) / 256, 256, 0, stream>>>(
      Wrel0, Wroot0, Wrel1, Wroot1, Wrel2, Wroot2, Wpack,
      x, drop0, drop1, drop2, hdA, kb1, kb2, n4, ncnt, Npad,
      (uint4*)nlist, nL4, NW);

  const int nchunk = (E + 255) / 256;
  fillb_kernel<<<nchunk * NSEG, 256, 0, stream>>>(eidx, ncnt, nlist, E, segsz);

  // layer 0: hdA -> hdB (relu + drop1 fused)
  layer_kernel<<<nbuck16, 256, 0, stream>>>(hdA, ncnt, nlist, Wp0, b0, kb1,
                                            hdB, 1, N);
  // layer 1: hdB -> hdA (relu + drop2 fused)
  layer_kernel<<<nbuck16, 256, 0, stream>>>(hdB, ncnt, nlist, Wp1, b1, kb2,
                                            hdA, 1, N);
  // layer 2: hdA -> d_out (fp32)
  layer_kernel<<<nbuck16, 256, 0, stream>>>(hdA, ncnt, nlist, Wp2, b2, nullptr,
                                            d_out, 0, N);
}